// Round 2
// baseline (490.069 us; speedup 1.0000x reference)
//
#include <hip/hip_runtime.h>
#include <hip/hip_bf16.h>

#define NT 512
#define TT 192
#define S_ 240
#define NB 16
#define T_ 16384
#define W_ 32
#define TW_ (T_ - W_)
#define SLOPE_C 0.22916666666666666f

__device__ __forceinline__ float rr(float v) { return v >= 0.f ? v : v * SLOPE_C; }

// Conv layer: out[c,p] = rrelu(bias[c] + sum_ci w[c,ci,0]*src[ci,p] + w[c,ci,1]*src[ci,p+D])
// wb layout: fp32, c*128 + ci*2 + k (straight copy of global (COUT,64,2))
template<int D, int COUT, int CBLK>
__device__ __forceinline__ void conv_layer(
    const float* __restrict__ src, float* __restrict__ dst,
    const float* __restrict__ wb, const float* __restrict__ cbias,
    int n_out, int tid)
{
  constexpr int CGRPS = COUT / CBLK;
  constexpr int PGRPS = NT / CGRPS;
  const int pg = tid % PGRPS;
  const int cg = tid / PGRPS;
  const int pbase = pg * 8;
  const int c0 = cg * CBLK;
  if (pbase < n_out) {
    float acc[CBLK][8];
#pragma unroll
    for (int q = 0; q < CBLK; ++q) {
      float bq = cbias[c0 + q];
#pragma unroll
      for (int j = 0; j < 8; ++j) acc[q][j] = bq;
    }
#pragma unroll 4
    for (int ci = 0; ci < 64; ++ci) {
      const float* row = src + ci * S_ + pbase;
      float a0[8], a1[8];
      if constexpr (D <= 4) {
        float win[12];
        *(float4*)&win[0] = *(const float4*)(row);
        *(float4*)&win[4] = *(const float4*)(row + 4);
        *(float4*)&win[8] = *(const float4*)(row + 8);
#pragma unroll
        for (int j = 0; j < 8; ++j) { a0[j] = win[j]; a1[j] = win[j + D]; }
      } else {
        *(float4*)&a0[0] = *(const float4*)(row);
        *(float4*)&a0[4] = *(const float4*)(row + 4);
        *(float4*)&a1[0] = *(const float4*)(row + D);
        *(float4*)&a1[4] = *(const float4*)(row + D + 4);
      }
#pragma unroll
      for (int q = 0; q < CBLK; ++q) {
        float2 wv = *(const float2*)(wb + (c0 + q) * 128 + ci * 2);
#pragma unroll
        for (int j = 0; j < 8; ++j) acc[q][j] += wv.x * a0[j] + wv.y * a1[j];
      }
    }
#pragma unroll
    for (int q = 0; q < CBLK; ++q)
#pragma unroll
      for (int j = 0; j < 8; ++j) {
        int p = pbase + j;
        if (p < n_out) dst[(c0 + q) * S_ + p] = rr(acc[q][j]);
      }
  }
}

__device__ __forceinline__ void stage_wf(float* dst, const float* g, int n4, int tid)
{
  const float4* g4 = (const float4*)g;
  float4* d4 = (float4*)dst;
  for (int i = tid; i < n4; i += NT) d4[i] = g4[i];
}

__global__ __launch_bounds__(NT) void kA(
    const float* __restrict__ x,
    const float* __restrict__ cw0, const float* __restrict__ cb0,
    const float* __restrict__ cw1, const float* __restrict__ cb1,
    const float* __restrict__ cw2, const float* __restrict__ cb2,
    const float* __restrict__ cw3, const float* __restrict__ cb3,
    const float* __restrict__ cw4, const float* __restrict__ cb4,
    const float* __restrict__ mw0, const float* __restrict__ mb0,
    const float* __restrict__ mw1, const float* __restrict__ mb1,
    const float* __restrict__ mw2, const float* __restrict__ mb2,
    const float* __restrict__ gum,
    float* __restrict__ ws_mus, float* __restrict__ out_gz)
{
  __shared__ float bufA[64 * S_];     // 60 KB
  __shared__ float bufB[64 * S_];     // 60 KB
  __shared__ float wbuf[8192];        // 32 KB (current layer weights, fp32)
  __shared__ float xbuf[S_ + 16];

  const int tile = blockIdx.x, b = blockIdx.y;
  const int t0 = tile * TT;
  const int core = (T_ - t0 < TT) ? (T_ - t0) : TT;
  const int tid = threadIdx.x;

  // stage padded x segment and layer-0 weights
  const int nx = core + 31;
  for (int i = tid; i < nx; i += NT) {
    int g = t0 + i;
    xbuf[i] = (g >= 31) ? x[b * T_ + g - 31] : 0.f;
  }
  stage_wf(wbuf, cw0, 32, tid);    // 128 floats
  __syncthreads();

  // layer 0: 1 -> 64, d=1
  const int n0 = core + 30;
  for (int i = tid; i < 64 * 256; i += NT) {
    int c = i >> 8, p = i & 255;
    if (p < n0) {
      float v = cb0[c] + wbuf[c * 2] * xbuf[p] + wbuf[c * 2 + 1] * xbuf[p + 1];
      bufA[c * S_ + p] = rr(v);
    }
  }
  __syncthreads();

  stage_wf(wbuf, cw1, 2048, tid);  // 8192 floats
  __syncthreads();
  conv_layer<2, 64, 4>(bufA, bufB, wbuf, cb1, core + 28, tid);
  __syncthreads();

  stage_wf(wbuf, cw2, 2048, tid);
  __syncthreads();
  conv_layer<4, 64, 4>(bufB, bufA, wbuf, cb2, core + 24, tid);
  __syncthreads();

  stage_wf(wbuf, cw3, 2048, tid);
  __syncthreads();
  conv_layer<8, 64, 4>(bufA, bufB, wbuf, cb3, core + 16, tid);
  __syncthreads();

  stage_wf(wbuf, cw4, 256, tid);   // 1024 floats
  __syncthreads();
  conv_layer<16, 8, 1>(bufB, bufA, wbuf, cb4, core, tid);  // h4 -> bufA rows 0..7
  __syncthreads();

  // stage MLP weights (wbuf free now) + softmax in parallel
  for (int i = tid; i < 256; i += NT) {
    wbuf[i] = mw0[i];
    wbuf[256 + i] = mw1[i];
  }
  if (tid < 16) {
    wbuf[512 + tid] = mw2[tid];
    wbuf[528 + tid] = mb0[tid];
    wbuf[544 + tid] = mb1[tid];
  }
  if (tid == 0) wbuf[560] = mb2[0];

  if (tid < core) {
    const int t = t0 + tid;
    float l[8];
#pragma unroll
    for (int r = 0; r < 8; ++r) l[r] = bufA[r * S_ + tid];
    float gv[8];
    *(float4*)&gv[0] = *(const float4*)(gum + (size_t)(b * T_ + t) * 8);
    *(float4*)&gv[4] = *(const float4*)(gum + (size_t)(b * T_ + t) * 8 + 4);
    float s[8], mx = -1e30f;
#pragma unroll
    for (int r = 0; r < 8; ++r) { s[r] = (l[r] + gv[r]) * 10.0f; mx = fmaxf(mx, s[r]); }
    float e[8], sum = 0.f;
#pragma unroll
    for (int r = 0; r < 8; ++r) { e[r] = __expf(s[r] - mx); sum += e[r]; }
    float inv = 1.0f / sum;
#pragma unroll
    for (int r = 0; r < 8; ++r) {
      float z = e[r] * inv;
      bufB[r * S_ + tid] = z;   // keep fp32 gen_z for the MLP
      out_gz[(size_t)(b * 8 + r) * T_ + t] = z;
    }
  }
  __syncthreads();

  // pointwise MLP: cat(gen_z, h4) -> 16 -> 16 -> 1 (mus)
  if (tid < core) {
    float gz[8], hh[8];
#pragma unroll
    for (int r = 0; r < 8; ++r) { gz[r] = bufB[r * S_ + tid]; hh[r] = bufA[r * S_ + tid]; }
    float m0[16];
#pragma unroll
    for (int o = 0; o < 16; ++o) {
      float a = wbuf[528 + o];
#pragma unroll
      for (int i = 0; i < 8; ++i) a += wbuf[o * 16 + i] * gz[i];
#pragma unroll
      for (int i = 0; i < 8; ++i) a += wbuf[o * 16 + 8 + i] * hh[i];
      m0[o] = rr(a);
    }
    float m1[16];
#pragma unroll
    for (int o = 0; o < 16; ++o) {
      float a = wbuf[544 + o];
#pragma unroll
      for (int i = 0; i < 16; ++i) a += wbuf[256 + o * 16 + i] * m0[i];
      m1[o] = rr(a);
    }
    float mu = wbuf[560];
#pragma unroll
    for (int i = 0; i < 16; ++i) mu += wbuf[512 + i] * m1[i];
    ws_mus[b * T_ + t0 + tid] = mu;
  }
}

// _mus[b,t'] = mus[b,W+t'] - cov[b,W+t'] * sum_w fj[b,w,W+t'] * (x[b,w+t'] - mus[b,w+t'])
__global__ __launch_bounds__(256) void kB(
    const float* __restrict__ x, const float* __restrict__ fish,
    const float* __restrict__ sct, const float* __restrict__ ws_mus,
    const float* __restrict__ gz, float* __restrict__ out0)
{
  __shared__ float xm[288], mm[288], fs[256], sc[8];
  const int b = blockIdx.y;
  const int s = blockIdx.x * 256;
  const int tid = threadIdx.x;
  for (int i = tid; i < 288; i += 256) {
    int g = s + i;
    bool ok = g < T_;
    xm[i] = ok ? x[b * T_ + g] : 0.f;
    mm[i] = ok ? ws_mus[b * T_ + g] : 0.f;
  }
  fs[tid] = fish[tid];
  if (tid < 8) sc[tid] = sct[tid];
  __syncthreads();
  const int tp = s + tid;
  if (tp < TW_) {
    const int t = W_ + tp;
    float z[8];
#pragma unroll
    for (int r = 0; r < 8; ++r) z[r] = gz[(size_t)(b * 8 + r) * T_ + t];
    float cv = 0.f;
#pragma unroll
    for (int r = 0; r < 8; ++r) cv += sc[r] * z[r];
    cv *= cv;
    float acc = 0.f;
#pragma unroll 4
    for (int w = 0; w < 32; ++w) {
      float fj = 0.f;
#pragma unroll
      for (int r = 0; r < 8; ++r) fj += z[r] * fs[r * 32 + w];
      acc += fj * (xm[tid + w] - mm[tid + w]);
    }
    out0[b * TW_ + tp] = mm[tid + 32] - cv * acc;
  }
}

extern "C" void kernel_launch(void* const* d_in, const int* in_sizes, int n_in,
                              void* d_out, int out_size, void* d_ws, size_t ws_size,
                              hipStream_t stream)
{
  const float* x   = (const float*)d_in[0];
  const float* cw0 = (const float*)d_in[1];
  const float* cb0 = (const float*)d_in[2];
  const float* cw1 = (const float*)d_in[3];
  const float* cb1 = (const float*)d_in[4];
  const float* cw2 = (const float*)d_in[5];
  const float* cb2 = (const float*)d_in[6];
  const float* cw3 = (const float*)d_in[7];
  const float* cb3 = (const float*)d_in[8];
  const float* cw4 = (const float*)d_in[9];
  const float* cb4 = (const float*)d_in[10];
  const float* mw0 = (const float*)d_in[11];
  const float* mb0 = (const float*)d_in[12];
  const float* mw1 = (const float*)d_in[13];
  const float* mb1 = (const float*)d_in[14];
  const float* mw2 = (const float*)d_in[15];
  const float* mb2 = (const float*)d_in[16];
  const float* sct = (const float*)d_in[17];
  const float* fish= (const float*)d_in[18];
  const float* gum = (const float*)d_in[19];

  float* out0   = (float*)d_out;         // _mus: (16, 16352)
  float* out_gz = out0 + NB * TW_;       // gen_z: (16, 8, 16384)
  float* ws_mus = (float*)d_ws;          // B*T fp32 mus

  dim3 gA((T_ + TT - 1) / TT, NB);       // (86, 16)
  kA<<<gA, NT, 0, stream>>>(x, cw0, cb0, cw1, cb1, cw2, cb2, cw3, cb3, cw4, cb4,
                            mw0, mb0, mw1, mb1, mw2, mb2, gum, ws_mus, out_gz);
  dim3 gB((TW_ + 255) / 256, NB);        // (64, 16)
  kB<<<gB, 256, 0, stream>>>(x, fish, sct, ws_mus, out_gz, out0);
}

// Round 6
// 281.338 us; speedup vs baseline: 1.7419x; 1.7419x over previous
//
#include <hip/hip_runtime.h>
#include <hip/hip_bf16.h>

#define NT 512
#define TT 192
#define PBA 222     // bufA rows (L0/L2 output)
#define PBB 220     // bufB rows (L1/L3 output)
#define NB 16
#define T_ 16384
#define W_ 32
#define TW_ (T_ - W_)
#define SLOPE_C 0.22916666666666666f

typedef short v8s __attribute__((ext_vector_type(8)));
typedef float v4f __attribute__((ext_vector_type(4)));

__device__ __forceinline__ float rr(float v){ return v >= 0.f ? v : v * SLOPE_C; }
__device__ __forceinline__ ushort f2bs(float f){ __hip_bfloat16 h = __float2bfloat16(f); return *(ushort*)&h; }
__device__ __forceinline__ float bs2f(ushort u){ union{unsigned i; float f;} v; v.i = ((unsigned)u) << 16; return v.f; }

// swizzled fp32 act index: row stride 64 floats, 8-float groups XOR'd by row&7
__device__ __forceinline__ int aidx(int p, int c){
  return p*64 + ((((c >> 3) ^ (p & 7)) << 3) | (c & 7));
}
// swizzled bf16 weight index: wr = plane*128 + tap*64 + cout, 64 ushorts/row
__device__ __forceinline__ int widx(int wr, int ci){
  return wr*64 + ((((ci >> 3) ^ (wr & 7)) << 3) | (ci & 7));
}

// commit 16 prefetched fp32 weights/thread (global layout (64,64,2)) into 3 bf16 planes
__device__ __forceinline__ void scatter_w(const float4 w[4], ushort* wlds, int tid){
#pragma unroll
  for (int j = 0; j < 4; ++j){
    const float* e = (const float*)&w[j];
#pragma unroll
    for (int q = 0; q < 4; ++q){
      int l = (tid + j*NT)*4 + q;
      int c = l >> 7, rem = l & 127, ci = rem >> 1, k = rem & 1;
      float v = e[q];
      ushort h = f2bs(v);
      float r1 = v - bs2f(h);
      ushort m = f2bs(r1);
      ushort lo = f2bs(r1 - bs2f(m));
      int wr = k*64 + c;
      wlds[widx(wr, ci)]       = h;
      wlds[widx(128 + wr, ci)] = m;
      wlds[widx(256 + wr, ci)] = lo;
    }
  }
}

// 64ch->64ch dilated conv on MFMA, fp32-exact via 3-way bf16 decomposition.
// src/dst are swizzled fp32 act buffers; wave w<7 computes positions [w*32, w*32+32)
template<int D, int NSRC, int NDST>
__device__ __forceinline__ void mfma_layer(const float* __restrict__ src,
    float* __restrict__ dst, const ushort* __restrict__ wlds,
    const float* __restrict__ cbias, int tid)
{
  const int wave = tid >> 6;
  if (wave >= 7) return;
  const int lane = tid & 63;
  const int n = lane & 15, quad = lane >> 4;
  const int p0 = wave * 32;

  v4f acc[8];
  const v4f vz = {0.f, 0.f, 0.f, 0.f};
#pragma unroll
  for (int i = 0; i < 8; ++i) acc[i] = vz;

#pragma unroll
  for (int tap = 0; tap < 2; ++tap){
#pragma unroll
    for (int kb = 0; kb < 2; ++kb){
      const int g = kb*4 + quad;                 // 8-elem k-group index
      v8s w0f[4], w1f[4], w2f[4];
#pragma unroll
      for (int mt = 0; mt < 4; ++mt){
        int wr = tap*64 + mt*16 + n;
        const ushort* wp = wlds + wr*64 + ((g ^ (wr & 7)) << 3);
        w0f[mt] = *(const v8s*)wp;
        w1f[mt] = *(const v8s*)(wp + 128*64);
        w2f[mt] = *(const v8s*)(wp + 256*64);
      }
      v8s a0[2], a1[2], a2[2];
#pragma unroll
      for (int nt = 0; nt < 2; ++nt){
        int p = p0 + nt*16 + n + tap*D;
        if (p >= NSRC) p = NSRC - 1;             // clamp: touches invalid outputs only
        const float* ap = src + p*64 + ((g ^ (p & 7)) << 3);
        float av[8];
        *(float4*)&av[0] = *(const float4*)ap;
        *(float4*)&av[4] = *(const float4*)(ap + 4);
        v8s t0, t1, t2;
#pragma unroll
        for (int j = 0; j < 8; ++j){
          float v = av[j];
          ushort h = f2bs(v);
          float r1 = v - bs2f(h);
          ushort m = f2bs(r1);
          ushort lo = f2bs(r1 - bs2f(m));
          t0[j] = (short)h; t1[j] = (short)m; t2[j] = (short)lo;
        }
        a0[nt] = t0; a1[nt] = t1; a2[nt] = t2;
      }
#pragma unroll
      for (int nt = 0; nt < 2; ++nt)
#pragma unroll
        for (int mt = 0; mt < 4; ++mt){
          v4f a = acc[nt*4 + mt];
          a = __builtin_amdgcn_mfma_f32_16x16x32_bf16(w0f[mt], a0[nt], a, 0, 0, 0);
          a = __builtin_amdgcn_mfma_f32_16x16x32_bf16(w0f[mt], a1[nt], a, 0, 0, 0);
          a = __builtin_amdgcn_mfma_f32_16x16x32_bf16(w1f[mt], a0[nt], a, 0, 0, 0);
          a = __builtin_amdgcn_mfma_f32_16x16x32_bf16(w0f[mt], a2[nt], a, 0, 0, 0);
          a = __builtin_amdgcn_mfma_f32_16x16x32_bf16(w1f[mt], a1[nt], a, 0, 0, 0);
          a = __builtin_amdgcn_mfma_f32_16x16x32_bf16(w2f[mt], a0[nt], a, 0, 0, 0);
          acc[nt*4 + mt] = a;
        }
    }
  }

  // epilogue: D layout col=lane&15 (pos), row=quad*4+r (cout); store fp32 (exact)
#pragma unroll
  for (int nt = 0; nt < 2; ++nt){
    int p = p0 + nt*16 + n;
    if (p < NDST){
#pragma unroll
      for (int mt = 0; mt < 4; ++mt){
#pragma unroll
        for (int r = 0; r < 4; r += 2){
          int c = mt*16 + quad*4 + r;
          float y0 = rr(acc[nt*4 + mt][r]     + cbias[c]);
          float y1 = rr(acc[nt*4 + mt][r + 1] + cbias[c + 1]);
          float* dp = dst + p*64 + ((((c >> 3) ^ (p & 7)) << 3) | (c & 7));
          *(float2*)dp = make_float2(y0, y1);
        }
      }
    }
  }
}

__global__ __launch_bounds__(NT) void kA(
    const float* __restrict__ x,
    const float* __restrict__ cw0, const float* __restrict__ cb0,
    const float* __restrict__ cw1, const float* __restrict__ cb1,
    const float* __restrict__ cw2, const float* __restrict__ cb2,
    const float* __restrict__ cw3, const float* __restrict__ cb3,
    const float* __restrict__ cw4, const float* __restrict__ cb4,
    const float* __restrict__ mw0, const float* __restrict__ mb0,
    const float* __restrict__ mw1, const float* __restrict__ mb1,
    const float* __restrict__ mw2, const float* __restrict__ mb2,
    const float* __restrict__ gum,
    float* __restrict__ ws_mus, float* __restrict__ out_gz)
{
  __shared__ float  bufA[PBA*64];      // 56,832 B
  __shared__ float  bufB[PBB*64];      // 56,320 B
  __shared__ ushort wlds[3*128*64];    // 49,152 B   (total 162,304 B)

  float* xbuf = bufB;                  // alias: dead before L1 writes bufB
  float* w0_s = bufB + 224;

  const int tile = blockIdx.x, b = blockIdx.y;
  const int t0 = tile * TT;
  const int core = (T_ - t0 < TT) ? (T_ - t0) : TT;
  const int tid = threadIdx.x;

  // prefetch full W1 (8192 floats) into regs
  float4 wpre[4];
  { const float4* g = (const float4*)cw1;
    wpre[0] = g[tid]; wpre[1] = g[tid + NT];
    wpre[2] = g[tid + 2*NT]; wpre[3] = g[tid + 3*NT]; }

  // Phase A: stage padded x and w0
  const int nx = core + 31;
  for (int i = tid; i < nx; i += NT){
    int g = t0 + i;
    xbuf[i] = (g >= 31) ? x[(size_t)b*T_ + g - 31] : 0.f;
  }
  if (tid < 128) w0_s[tid] = cw0[tid];
  __syncthreads();

  // Phase B: commit W1, prefetch W2, layer0 (1->64, d=1) fp32 VALU
  scatter_w(wpre, wlds, tid);
  { const float4* g = (const float4*)cw2;
    wpre[0] = g[tid]; wpre[1] = g[tid + NT];
    wpre[2] = g[tid + 2*NT]; wpre[3] = g[tid + 3*NT]; }
  {
    const int n0 = core + 30;
    for (int i = tid; i < 224*64; i += NT){
      int p = i >> 6, c = i & 63;
      if (p < PBA){
        float y = 0.f;
        if (p < n0) y = rr(cb0[c] + w0_s[2*c]*xbuf[p] + w0_s[2*c + 1]*xbuf[p + 1]);
        bufA[aidx(p, c)] = y;
      }
    }
  }
  __syncthreads();

  mfma_layer<2, PBA, PBB>(bufA, bufB, wlds, cb1, tid);   // layer1
  __syncthreads();
  scatter_w(wpre, wlds, tid);
  { const float4* g = (const float4*)cw3;
    wpre[0] = g[tid]; wpre[1] = g[tid + NT];
    wpre[2] = g[tid + 2*NT]; wpre[3] = g[tid + 3*NT]; }
  __syncthreads();
  mfma_layer<4, PBB, PBA>(bufB, bufA, wlds, cb2, tid);   // layer2
  __syncthreads();
  scatter_w(wpre, wlds, tid);
  __syncthreads();
  mfma_layer<8, PBA, PBB>(bufA, bufB, wlds, cb3, tid);   // layer3 -> bufB
  __syncthreads();

  // Phase H: stage layer4 + MLP weights fp32 into wlds region (free now)
  float* w4s  = (float*)wlds;          // 1024 floats
  float* mlpw = w4s + 1024;            // mw0(256) mw1(256) mw2(16) mb0(16) mb1(16) mb2(1)
  for (int i = tid; i < 1024; i += NT) w4s[i] = cw4[i];
  for (int i = tid; i < 256; i += NT){ mlpw[i] = mw0[i]; mlpw[256 + i] = mw1[i]; }
  if (tid < 16){ mlpw[512 + tid] = mw2[tid]; mlpw[528 + tid] = mb0[tid]; mlpw[544 + tid] = mb1[tid]; }
  if (tid == 0) mlpw[560] = mb2[0];
  __syncthreads();

  // Phase I: layer4 (64->8, d=16) fp32 VALU; h4 into bufA region (L2 data dead)
  // NOTE: reference applies rrelu after EVERY conv including this one.
  float* h4s = bufA;                   // [8][TT]
  for (int i = tid; i < 8*TT; i += NT){
    int c4 = i / TT, p = i - c4*TT;
    if (p < core){
      float a = cb4[c4];
      const float* wc = w4s + c4*128;
#pragma unroll 8
      for (int ci = 0; ci < 64; ++ci){
        float a0v = bufB[aidx(p, ci)];
        float a1v = bufB[aidx(p + 16, ci)];
        a += wc[2*ci]*a0v + wc[2*ci + 1]*a1v;
      }
      h4s[c4*TT + p] = rr(a);          // <-- the R4/R5 bug: rrelu was missing
    }
  }
  __syncthreads();

  // Phase J: softmax + pointwise MLP per position
  if (tid < core){
    const int t = t0 + tid;
    float l[8];
#pragma unroll
    for (int r = 0; r < 8; ++r) l[r] = h4s[r*TT + tid];
    float gv[8];
    *(float4*)&gv[0] = *(const float4*)(gum + (size_t)(b*T_ + t)*8);
    *(float4*)&gv[4] = *(const float4*)(gum + (size_t)(b*T_ + t)*8 + 4);
    float s[8], mx = -1e30f;
#pragma unroll
    for (int r = 0; r < 8; ++r){ s[r] = (l[r] + gv[r]) * 10.0f; mx = fmaxf(mx, s[r]); }
    float e[8], sum = 0.f;
#pragma unroll
    for (int r = 0; r < 8; ++r){ e[r] = __expf(s[r] - mx); sum += e[r]; }
    float inv = 1.0f / sum;
    float z[8];
#pragma unroll
    for (int r = 0; r < 8; ++r){
      z[r] = e[r] * inv;
      out_gz[(size_t)(b*8 + r)*T_ + t] = z[r];
    }
    float m0[16];
#pragma unroll
    for (int o = 0; o < 16; ++o){
      float a = mlpw[528 + o];
#pragma unroll
      for (int i = 0; i < 8; ++i) a += mlpw[o*16 + i] * z[i];
#pragma unroll
      for (int i = 0; i < 8; ++i) a += mlpw[o*16 + 8 + i] * l[i];
      m0[o] = rr(a);
    }
    float m1[16];
#pragma unroll
    for (int o = 0; o < 16; ++o){
      float a = mlpw[544 + o];
#pragma unroll
      for (int i = 0; i < 16; ++i) a += mlpw[256 + o*16 + i] * m0[i];
      m1[o] = rr(a);
    }
    float mu = mlpw[560];
#pragma unroll
    for (int i = 0; i < 16; ++i) mu += mlpw[512 + i] * m1[i];
    ws_mus[(size_t)b*T_ + t] = mu;
  }
}

__global__ __launch_bounds__(256) void kB(
    const float* __restrict__ x, const float* __restrict__ fish,
    const float* __restrict__ sct, const float* __restrict__ ws_mus,
    const float* __restrict__ gz, float* __restrict__ out0)
{
  __shared__ float xm[288], mm[288], fs[256], sc[8];
  const int b = blockIdx.y;
  const int s = blockIdx.x * 256;
  const int tid = threadIdx.x;
  for (int i = tid; i < 288; i += 256){
    int g = s + i;
    bool ok = g < T_;
    xm[i] = ok ? x[(size_t)b*T_ + g] : 0.f;
    mm[i] = ok ? ws_mus[(size_t)b*T_ + g] : 0.f;
  }
  fs[tid] = fish[tid];
  if (tid < 8) sc[tid] = sct[tid];
  __syncthreads();
  const int tp = s + tid;
  if (tp < TW_){
    const int t = W_ + tp;
    float z[8];
#pragma unroll
    for (int r = 0; r < 8; ++r) z[r] = gz[(size_t)(b*8 + r)*T_ + t];
    float cv = 0.f;
#pragma unroll
    for (int r = 0; r < 8; ++r) cv += sc[r] * z[r];
    cv *= cv;
    float acc = 0.f;
#pragma unroll 4
    for (int w = 0; w < 32; ++w){
      float fj = 0.f;
#pragma unroll
      for (int r = 0; r < 8; ++r) fj += z[r] * fs[r*32 + w];
      acc += fj * (xm[tid + w] - mm[tid + w]);
    }
    out0[(size_t)b*TW_ + tp] = mm[tid + 32] - cv * acc;
  }
}

extern "C" void kernel_launch(void* const* d_in, const int* in_sizes, int n_in,
                              void* d_out, int out_size, void* d_ws, size_t ws_size,
                              hipStream_t stream)
{
  const float* x   = (const float*)d_in[0];
  const float* cw0 = (const float*)d_in[1];
  const float* cb0 = (const float*)d_in[2];
  const float* cw1 = (const float*)d_in[3];
  const float* cb1 = (const float*)d_in[4];
  const float* cw2 = (const float*)d_in[5];
  const float* cb2 = (const float*)d_in[6];
  const float* cw3 = (const float*)d_in[7];
  const float* cb3 = (const float*)d_in[8];
  const float* cw4 = (const float*)d_in[9];
  const float* cb4 = (const float*)d_in[10];
  const float* mw0 = (const float*)d_in[11];
  const float* mb0 = (const float*)d_in[12];
  const float* mw1 = (const float*)d_in[13];
  const float* mb1 = (const float*)d_in[14];
  const float* mw2 = (const float*)d_in[15];
  const float* mb2 = (const float*)d_in[16];
  const float* sct = (const float*)d_in[17];
  const float* fish= (const float*)d_in[18];
  const float* gum = (const float*)d_in[19];

  float* out0   = (float*)d_out;         // _mus: (16, 16352)
  float* out_gz = out0 + NB*TW_;         // gen_z: (16, 8, 16384)
  float* ws_mus = (float*)d_ws;          // B*T fp32 mus

  dim3 gA((T_ + TT - 1) / TT, NB);       // (86, 16)
  kA<<<gA, NT, 0, stream>>>(x, cw0, cb0, cw1, cb1, cw2, cb2, cw3, cb3, cw4, cb4,
                            mw0, mb0, mw1, mb1, mw2, mb2, gum, ws_mus, out_gz);
  dim3 gB((TW_ + 255) / 256, NB);        // (64, 16)
  kB<<<gB, 256, 0, stream>>>(x, fish, sct, ws_mus, out_gz, out0);
}

// Round 7
// 230.074 us; speedup vs baseline: 2.1301x; 1.2228x over previous
//
#include <hip/hip_runtime.h>
#include <hip/hip_bf16.h>

#define NT 512
#define TT 192
#define PBA 222     // bufA rows (L0/L2 output)
#define PBB 220     // bufB rows (L1/L3 output)
#define NB 16
#define T_ 16384
#define W_ 32
#define TW_ (T_ - W_)
#define SLOPE_C 0.22916666666666666f

typedef short v8s __attribute__((ext_vector_type(8)));
typedef float v4f __attribute__((ext_vector_type(4)));

__device__ __forceinline__ float rr(float v){ return v >= 0.f ? v : v * SLOPE_C; }
__device__ __forceinline__ ushort f2bs(float f){ __hip_bfloat16 h = __float2bfloat16(f); return *(ushort*)&h; }
__device__ __forceinline__ float bs2f(ushort u){ union{unsigned i; float f;} v; v.i = ((unsigned)u) << 16; return v.f; }

// Act row = 128 ushorts ([hi 64][lo 64]) = 16 granules of 8 ushorts (16 B).
// Physical granule = logical granule ^ (p & 15)  -> b128 reads are bank-uniform.
__device__ __forceinline__ int agr(int p, int gi){ return p*128 + ((gi ^ (p & 15)) << 3); }
// Weight row = 64 ushorts = 8 granules; physical = logical ^ (wr & 7)
__device__ __forceinline__ int widx(int wr, int ci){
  return wr*64 + ((((ci >> 3) ^ (wr & 7)) << 3) | (ci & 7));
}

// commit 16 prefetched fp32 weights/thread (global (64,64,2)) into 2 bf16 planes
__device__ __forceinline__ void scatter_w(const float4 w[4], ushort* wlds, int tid){
#pragma unroll
  for (int j = 0; j < 4; ++j){
    const float* e = (const float*)&w[j];
#pragma unroll
    for (int q = 0; q < 4; ++q){
      int l = (tid + j*NT)*4 + q;
      int c = l >> 7, rem = l & 127, ci = rem >> 1, k = rem & 1;
      float v = e[q];
      ushort h = f2bs(v);
      ushort lo = f2bs(v - bs2f(h));
      int wr = k*64 + c;
      int ix = widx(wr, ci);
      wlds[ix] = h;
      wlds[8192 + ix] = lo;
    }
  }
}

// 64->64 dilated conv on MFMA with hi/lo bf16 (3-term product).
template<int D, int NSRC, int NDST>
__device__ __forceinline__ void mfma_layer(const ushort* __restrict__ src,
    ushort* __restrict__ dst, const ushort* __restrict__ wlds,
    const float* __restrict__ cbias, int tid)
{
  const int wave = tid >> 6;
  if (wave >= 7) return;
  const int lane = tid & 63;
  const int n = lane & 15, quad = lane >> 4;
  const int p0 = wave * 32;

  v4f acc[8];
  const v4f vz = {0.f, 0.f, 0.f, 0.f};
#pragma unroll
  for (int i = 0; i < 8; ++i) acc[i] = vz;

#pragma unroll
  for (int tap = 0; tap < 2; ++tap){
#pragma unroll
    for (int kb = 0; kb < 2; ++kb){
      const int kg = kb*4 + quad;                // logical k-granule 0..7
      v8s wh[4], wl[4], ah[2], al[2];
#pragma unroll
      for (int mt = 0; mt < 4; ++mt){
        int wr = tap*64 + mt*16 + n;
        int base = wr*64 + ((kg ^ (wr & 7)) << 3);
        wh[mt] = *(const v8s*)(wlds + base);
        wl[mt] = *(const v8s*)(wlds + 8192 + base);
      }
#pragma unroll
      for (int nt = 0; nt < 2; ++nt){
        int p = p0 + nt*16 + n + tap*D;
        if (p >= NSRC) p = NSRC - 1;             // clamp: invalid outputs only
        ah[nt] = *(const v8s*)(src + agr(p, kg));
        al[nt] = *(const v8s*)(src + agr(p, 8 + kg));
      }
#pragma unroll
      for (int nt = 0; nt < 2; ++nt)
#pragma unroll
        for (int mt = 0; mt < 4; ++mt){
          v4f a = acc[nt*4 + mt];
          a = __builtin_amdgcn_mfma_f32_16x16x32_bf16(wh[mt], ah[nt], a, 0, 0, 0);
          a = __builtin_amdgcn_mfma_f32_16x16x32_bf16(wh[mt], al[nt], a, 0, 0, 0);
          a = __builtin_amdgcn_mfma_f32_16x16x32_bf16(wl[mt], ah[nt], a, 0, 0, 0);
          acc[nt*4 + mt] = a;
        }
    }
  }

  // epilogue: D col=lane&15 (pos), row=quad*4+r (cout); store hi/lo pairs
#pragma unroll
  for (int nt = 0; nt < 2; ++nt){
    int p = p0 + nt*16 + n;
    if (p < NDST){
#pragma unroll
      for (int mt = 0; mt < 4; ++mt){
#pragma unroll
        for (int r = 0; r < 4; r += 2){
          int c = mt*16 + quad*4 + r;
          float y0 = rr(acc[nt*4 + mt][r]     + cbias[c]);
          float y1 = rr(acc[nt*4 + mt][r + 1] + cbias[c + 1]);
          ushort h0 = f2bs(y0), h1 = f2bs(y1);
          ushort l0 = f2bs(y0 - bs2f(h0)), l1 = f2bs(y1 - bs2f(h1));
          int gh = agr(p, c >> 3)       + (c & 7);
          int gl = agr(p, 8 + (c >> 3)) + (c & 7);
          *(unsigned*)(dst + gh) = (unsigned)h0 | ((unsigned)h1 << 16);
          *(unsigned*)(dst + gl) = (unsigned)l0 | ((unsigned)l1 << 16);
        }
      }
    }
  }
}

template<bool GZT>
__global__ __launch_bounds__(NT) void kA(
    const float* __restrict__ x,
    const float* __restrict__ cw0, const float* __restrict__ cb0,
    const float* __restrict__ cw1, const float* __restrict__ cb1,
    const float* __restrict__ cw2, const float* __restrict__ cb2,
    const float* __restrict__ cw3, const float* __restrict__ cb3,
    const float* __restrict__ cw4, const float* __restrict__ cb4,
    const float* __restrict__ mw0, const float* __restrict__ mb0,
    const float* __restrict__ mw1, const float* __restrict__ mb1,
    const float* __restrict__ mw2, const float* __restrict__ mb2,
    const float* __restrict__ gum,
    float* __restrict__ ws_mus, float* __restrict__ out_gz,
    float* __restrict__ gzt)
{
  __shared__ ushort bufA[PBA*128];         // 56,832 B
  __shared__ ushort bufB[PBB*128];         // 56,320 B
  __shared__ ushort wlds[20480 + 1600];    // 44,160 B: W(2 planes) | W4(2 planes) | consts
  // total 157,312 B

  ushort* wlds4 = wlds + 16384;            // 2 planes x 32 rows x 64
  float*  cst   = (float*)(wlds + 20480);  // mlp/const staging (see offsets below)
  float*  xbuf  = (float*)bufB;            // alias: dead before L1 writes bufB

  const int tile = blockIdx.x, b = blockIdx.y;
  const int t0 = tile * TT;
  const int core = (T_ - t0 < TT) ? (T_ - t0) : TT;
  const int tid = threadIdx.x;

  // prefetch full W1 (8192 floats) into regs
  float4 wpre[4];
  { const float4* g = (const float4*)cw1;
    wpre[0] = g[tid]; wpre[1] = g[tid + NT];
    wpre[2] = g[tid + 2*NT]; wpre[3] = g[tid + 3*NT]; }

  // Phase A: stage x, W4 (2-split, zero-padded to M=16), consts
  const int nx = core + 31;
  for (int i = tid; i < nx; i += NT){
    int g = t0 + i;
    xbuf[i] = (g >= 31) ? x[(size_t)b*T_ + g - 31] : 0.f;
  }
  for (int l = tid; l < 1024; l += NT){            // cw4 (8,64,2)
    int c = l >> 7, rem = l & 127, ci = rem >> 1, k = rem & 1;
    float v = cw4[l];
    ushort h = f2bs(v); ushort lo = f2bs(v - bs2f(h));
    int ix = widx(k*16 + c, ci);
    wlds4[ix] = h;
    wlds4[2048 + ix] = lo;
  }
  for (int z = tid; z < 2048; z += NT){            // zero rows m=8..15
    int pl = z >> 10, rem = z & 1023, k = rem >> 9, rem2 = rem & 511;
    int m = 8 + (rem2 >> 6), ci = rem2 & 63;
    wlds4[pl*2048 + widx(k*16 + m, ci)] = 0;
  }
  for (int i = tid; i < 256; i += NT){ cst[i] = mw0[i]; cst[256 + i] = mw1[i]; }
  if (tid < 16){ cst[512+tid] = mw2[tid]; cst[528+tid] = mb0[tid]; cst[544+tid] = mb1[tid]; }
  if (tid == 0) cst[560] = mb2[0];
  if (tid < 8)   cst[576+tid] = cb4[tid];
  if (tid < 128) cst[592+tid] = cw0[tid];
  if (tid < 64)  cst[720+tid] = cb0[tid];
  __syncthreads();

  // Phase B: commit W1, prefetch W2, layer0 (1->64, d=1) VALU
  scatter_w(wpre, wlds, tid);
  { const float4* g = (const float4*)cw2;
    wpre[0] = g[tid]; wpre[1] = g[tid + NT];
    wpre[2] = g[tid + 2*NT]; wpre[3] = g[tid + 3*NT]; }
  {
    const int n0 = core + 30;
    for (int i = tid; i < PBA*64; i += NT){
      int p = i >> 6, c = i & 63;
      float y = 0.f;
      if (p < n0) y = rr(cst[720 + c] + cst[592 + 2*c]*xbuf[p] + cst[593 + 2*c]*xbuf[p + 1]);
      ushort h = f2bs(y); ushort lo = f2bs(y - bs2f(h));
      bufA[agr(p, c >> 3)       + (c & 7)] = h;
      bufA[agr(p, 8 + (c >> 3)) + (c & 7)] = lo;
    }
  }
  __syncthreads();

  mfma_layer<2, PBA, PBB>(bufA, bufB, wlds, cb1, tid);   // layer1
  __syncthreads();
  scatter_w(wpre, wlds, tid);
  { const float4* g = (const float4*)cw3;
    wpre[0] = g[tid]; wpre[1] = g[tid + NT];
    wpre[2] = g[tid + 2*NT]; wpre[3] = g[tid + 3*NT]; }
  __syncthreads();
  mfma_layer<4, PBB, PBA>(bufB, bufA, wlds, cb2, tid);   // layer2
  __syncthreads();
  scatter_w(wpre, wlds, tid);
  __syncthreads();
  mfma_layer<8, PBA, PBB>(bufA, bufB, wlds, cb3, tid);   // layer3 -> bufB
  __syncthreads();

  // Layer4 (64->8, d=16) on MFMA: M=16 tile, rows 8..15 zero
  float* h4s = (float*)bufA;           // [8][TT] fp32 (L2 data dead)
  {
    const int wave = tid >> 6;
    if (wave < 7){
      const int lane = tid & 63;
      const int n = lane & 15, quad = lane >> 4;
      const int p0 = wave * 32;
      v4f acc2[2];
      const v4f vz = {0.f, 0.f, 0.f, 0.f};
      acc2[0] = vz; acc2[1] = vz;
#pragma unroll
      for (int tap = 0; tap < 2; ++tap){
#pragma unroll
        for (int kb = 0; kb < 2; ++kb){
          const int kg = kb*4 + quad;
          int wr = tap*16 + n;
          int base = wr*64 + ((kg ^ (wr & 7)) << 3);
          v8s wh = *(const v8s*)(wlds4 + base);
          v8s wl = *(const v8s*)(wlds4 + 2048 + base);
#pragma unroll
          for (int nt = 0; nt < 2; ++nt){
            int p = p0 + nt*16 + n + tap*16;
            if (p >= PBB) p = PBB - 1;
            v8s ah = *(const v8s*)(bufB + agr(p, kg));
            v8s al = *(const v8s*)(bufB + agr(p, 8 + kg));
            v4f a = acc2[nt];
            a = __builtin_amdgcn_mfma_f32_16x16x32_bf16(wh, ah, a, 0, 0, 0);
            a = __builtin_amdgcn_mfma_f32_16x16x32_bf16(wh, al, a, 0, 0, 0);
            a = __builtin_amdgcn_mfma_f32_16x16x32_bf16(wl, ah, a, 0, 0, 0);
            acc2[nt] = a;
          }
        }
      }
#pragma unroll
      for (int nt = 0; nt < 2; ++nt){
        int p = p0 + nt*16 + n;
        if (p < core && quad < 2){
#pragma unroll
          for (int r = 0; r < 4; ++r){
            int c = quad*4 + r;
            h4s[c*TT + p] = rr(acc2[nt][r] + cst[576 + c]);
          }
        }
      }
    }
  }
  __syncthreads();

  // Phase J: softmax + pointwise MLP per position
  if (tid < core){
    const int t = t0 + tid;
    float l[8];
#pragma unroll
    for (int r = 0; r < 8; ++r) l[r] = h4s[r*TT + tid];
    float gv[8];
    *(float4*)&gv[0] = *(const float4*)(gum + (size_t)(b*T_ + t)*8);
    *(float4*)&gv[4] = *(const float4*)(gum + (size_t)(b*T_ + t)*8 + 4);
    float s[8], mx = -1e30f;
#pragma unroll
    for (int r = 0; r < 8; ++r){ s[r] = (l[r] + gv[r]) * 10.0f; mx = fmaxf(mx, s[r]); }
    float e[8], sum = 0.f;
#pragma unroll
    for (int r = 0; r < 8; ++r){ e[r] = __expf(s[r] - mx); sum += e[r]; }
    float inv = 1.0f / sum;
    float z[8];
#pragma unroll
    for (int r = 0; r < 8; ++r){
      z[r] = e[r] * inv;
      out_gz[(size_t)(b*8 + r)*T_ + t] = z[r];
    }
    if (GZT){
      *(float4*)(gzt + (size_t)(b*T_ + t)*8)     = make_float4(z[0], z[1], z[2], z[3]);
      *(float4*)(gzt + (size_t)(b*T_ + t)*8 + 4) = make_float4(z[4], z[5], z[6], z[7]);
    }
    float m0[16];
#pragma unroll
    for (int o = 0; o < 16; ++o){
      float a = cst[528 + o];
#pragma unroll
      for (int i = 0; i < 8; ++i) a += cst[o*16 + i] * z[i];
#pragma unroll
      for (int i = 0; i < 8; ++i) a += cst[o*16 + 8 + i] * l[i];
      m0[o] = rr(a);
    }
    float m1[16];
#pragma unroll
    for (int o = 0; o < 16; ++o){
      float a = cst[544 + o];
#pragma unroll
      for (int i = 0; i < 16; ++i) a += cst[256 + o*16 + i] * m0[i];
      m1[o] = rr(a);
    }
    float mu = cst[560];
#pragma unroll
    for (int i = 0; i < 16; ++i) mu += cst[512 + i] * m1[i];
    ws_mus[(size_t)b*T_ + t] = mu;
  }
}

template<bool GZT>
__global__ __launch_bounds__(256) void kB(
    const float* __restrict__ x, const float* __restrict__ fish,
    const float* __restrict__ sct, const float* __restrict__ ws_mus,
    const float* __restrict__ gz, float* __restrict__ out0)
{
  __shared__ float xm[288], mm[288], fs[256], sc[8];
  const int b = blockIdx.y;
  const int s = blockIdx.x * 256;
  const int tid = threadIdx.x;
  for (int i = tid; i < 288; i += 256){
    int g = s + i;
    bool ok = g < T_;
    xm[i] = ok ? x[(size_t)b*T_ + g] : 0.f;
    mm[i] = ok ? ws_mus[(size_t)b*T_ + g] : 0.f;
  }
  fs[tid] = fish[tid];
  if (tid < 8) sc[tid] = sct[tid];
  __syncthreads();
  const int tp = s + tid;
  if (tp < TW_){
    const int t = W_ + tp;
    float z[8];
    if (GZT){
      *(float4*)&z[0] = *(const float4*)(gz + (size_t)(b*T_ + t)*8);
      *(float4*)&z[4] = *(const float4*)(gz + (size_t)(b*T_ + t)*8 + 4);
    } else {
#pragma unroll
      for (int r = 0; r < 8; ++r) z[r] = gz[(size_t)(b*8 + r)*T_ + t];
    }
    float cv = 0.f;
#pragma unroll
    for (int r = 0; r < 8; ++r) cv += sc[r] * z[r];
    cv *= cv;
    float acc = 0.f;
#pragma unroll 4
    for (int w = 0; w < 32; ++w){
      float fj = 0.f;
#pragma unroll
      for (int r = 0; r < 8; ++r) fj += z[r] * fs[r*32 + w];
      acc += fj * (xm[tid + w] - mm[tid + w]);
    }
    out0[(size_t)b*TW_ + tp] = mm[tid + 32] - cv * acc;
  }
}

extern "C" void kernel_launch(void* const* d_in, const int* in_sizes, int n_in,
                              void* d_out, int out_size, void* d_ws, size_t ws_size,
                              hipStream_t stream)
{
  const float* x   = (const float*)d_in[0];
  const float* cw0 = (const float*)d_in[1];
  const float* cb0 = (const float*)d_in[2];
  const float* cw1 = (const float*)d_in[3];
  const float* cb1 = (const float*)d_in[4];
  const float* cw2 = (const float*)d_in[5];
  const float* cb2 = (const float*)d_in[6];
  const float* cw3 = (const float*)d_in[7];
  const float* cb3 = (const float*)d_in[8];
  const float* cw4 = (const float*)d_in[9];
  const float* cb4 = (const float*)d_in[10];
  const float* mw0 = (const float*)d_in[11];
  const float* mb0 = (const float*)d_in[12];
  const float* mw1 = (const float*)d_in[13];
  const float* mb1 = (const float*)d_in[14];
  const float* mw2 = (const float*)d_in[15];
  const float* mb2 = (const float*)d_in[16];
  const float* sct = (const float*)d_in[17];
  const float* fish= (const float*)d_in[18];
  const float* gum = (const float*)d_in[19];

  float* out0   = (float*)d_out;         // _mus: (16, 16352)
  float* out_gz = out0 + NB*TW_;         // gen_z: (16, 8, 16384)
  float* ws_mus = (float*)d_ws;          // B*T fp32 mus
  float* gzt    = ws_mus + (size_t)NB*T_;// optional transposed gen_z (b,t,r)

  const bool use_t = ws_size >= (size_t)NB*T_*9*sizeof(float);

  dim3 gA((T_ + TT - 1) / TT, NB);       // (86, 16)
  dim3 gB((TW_ + 255) / 256, NB);        // (64, 16)
  if (use_t){
    kA<true><<<gA, NT, 0, stream>>>(x, cw0, cb0, cw1, cb1, cw2, cb2, cw3, cb3, cw4, cb4,
                                    mw0, mb0, mw1, mb1, mw2, mb2, gum, ws_mus, out_gz, gzt);
    kB<true><<<gB, 256, 0, stream>>>(x, fish, sct, ws_mus, gzt, out0);
  } else {
    kA<false><<<gA, NT, 0, stream>>>(x, cw0, cb0, cw1, cb1, cw2, cb2, cw3, cb3, cw4, cb4,
                                     mw0, mb0, mw1, mb1, mw2, mb2, gum, ws_mus, out_gz, gzt);
    kB<false><<<gB, 256, 0, stream>>>(x, fish, sct, ws_mus, out_gz, out0);
  }
}